// Round 17
// baseline (292.540 us; speedup 1.0000x reference)
//
#include <hip/hip_runtime.h>
#include <cstdint>

// v5: 6-kernel train. v4 minus k_as1 — AS1+dflat fused into pool1's blocks
// (TMP/dflat live in LDS, never hit global; x1 branch untouched).
//  memset(8.4MB)                          zero WadjT/Adn/wsum
//  k_p0        <<<256,1024>>> 16KB LDS    XW = pos@W1 + edge scatter + wsum
//  k_gcn_s1    <<<256,1024>>> 31KB LDS    GCN+relu -> H + fused s1
//  k_pool1x1   <<<144,1024>>> 99KB LDS    pool1(+AS1, blk<16) + x1 (16..143)
//  k_conv2     <<<128,1024>>> 83KB LDS    conv2
//  k_s2pool2   <<<16,1024>>>  67KB LDS    s2 + pool2
//  k_final     <<<256,1024>>> 79KB LDS    x3+conv3 (blk<128) + agg + losses

#define WS_WADJT 0
#define WS_ADN   1048576
#define WS_WSUM  2097152
#define WS_XW    2101248
#define WS_H     4198400
#define WS_S1    6295552
#define WS_ADJ1  6823936
#define WS_X1    6889472
#define WS_X2    7413760
#define WS_S2    8200192
#define WS_ADJ2  8232960
#define WS_SCAL  8249344

// 1024-thread (16-wave) block reduction, red[16]
__device__ __forceinline__ float blockRedSum16(float v, float* red) {
  #pragma unroll
  for (int m = 32; m; m >>= 1) v += __shfl_xor(v, m);
  __syncthreads();
  if ((threadIdx.x & 63) == 0) red[threadIdx.x >> 6] = v;
  __syncthreads();
  float s = 0.f;
  #pragma unroll
  for (int i = 0; i < 16; ++i) s += red[i];
  __syncthreads();
  return s;
}

// ---------------- K1: XW = pos @ W1 ; edge scatter + wsum
__global__ __launch_bounds__(1024) void k_p0(const float* __restrict__ pos,
                                             const int* __restrict__ ei,
                                             const float* __restrict__ ea,
                                             const float* __restrict__ W1,
                                             float* __restrict__ ws) {
  __shared__ float sm[4096];
  int tid = threadIdx.x, blk = blockIdx.x;
  for (int i = tid; i < 4096; i += 1024) sm[i] = W1[i];
  __syncthreads();
  int col = tid & 63;
  #pragma unroll
  for (int pass = 0; pass < 8; ++pass) {
    int row = blk * 128 + pass * 16 + (tid >> 6);
    const float* a = pos + (size_t)row * 64;
    float acc = 0.f;
    #pragma unroll 8
    for (int k = 0; k < 64; ++k) acc += a[k] * sm[k * 64 + col];
    ws[WS_XW + (size_t)row * 64 + col] = acc;
  }
  if (tid < 256) {
    int e = blk * 256 + tid;
    int s = ei[e], d = ei[65536 + e];
    int g = s >> 8, r = s & 255, c = d & 255;
    float w = ea[e];
    atomicAdd(&ws[WS_WADJT + (size_t)(((g << 8) + c) << 8) + r], w);
    atomicAdd(&ws[WS_ADN + (size_t)(((g << 8) + r) << 8) + c], 1.0f);
    atomicAdd(&ws[WS_WSUM + (g << 8) + c], w);
  }
}

// ---------------- K2: GCN + relu -> H ; fused s1 (4 nodes x 4 iters)
__global__ __launch_bounds__(1024) void k_gcn_s1(float* __restrict__ ws,
                                                 const float* __restrict__ b1,
                                                 const float* __restrict__ p1W,
                                                 const float* __restrict__ p1b) {
  __shared__ float sm[7696];
  int tid = threadIdx.x, blk = blockIdx.x;
  float* sW = sm;                 // 4096 (p1W)
  float* dinvL = sm + 4096;       // 256
  float* pL = sm + 4352;          // 1024
  float* red4 = sm + 5376;        // 1024
  float* xm = sm + 6400;          // 256 (4 x 64)
  int* iL = (int*)(sm + 6656);    // 1024 ints
  int* wcnt = (int*)(sm + 7680);  // 16 ints
  int g = blk >> 4;
  for (int i = tid; i < 4096; i += 1024) sW[i] = p1W[i];
  if (tid < 256) dinvL[tid] = rsqrtf(ws[WS_WSUM + (g << 8) + tid] + 1.0f);
  __syncthreads();
  int ng = tid >> 8, ltid = tid & 255, lw = (tid >> 6) & 3, lane = tid & 63;
  float bb = b1[ltid & 63];
  for (int it = 0; it < 4; ++it) {
    int n = blk * 16 + it * 4 + ng;
    int cc = n & 255;
    float dn = dinvL[cc];
    float pv = ws[WS_WADJT + (size_t)n * 256 + ltid] * dinvL[ltid] * dn;
    if (ltid == cc) pv += dn * dn;
    bool act = (pv != 0.f);
    unsigned long long mask = __ballot(act);
    int wpos = (int)__popcll(mask & ((1ull << lane) - 1ull));
    if (lane == 0) wcnt[ng * 4 + lw] = (int)__popcll(mask);
    __syncthreads();
    int base = 0;
    #pragma unroll
    for (int i = 0; i < 4; ++i) base += (i < lw) ? wcnt[ng * 4 + i] : 0;
    int na = wcnt[ng * 4] + wcnt[ng * 4 + 1] + wcnt[ng * 4 + 2] + wcnt[ng * 4 + 3];
    if (act) { iL[ng * 256 + base + wpos] = ltid; pL[ng * 256 + base + wpos] = pv; }
    __syncthreads();
    const float* xg = ws + WS_XW + (size_t)g * 131072;
    float acc0 = 0.f, acc1 = 0.f;
    #pragma unroll 4
    for (int i = 0; i < na; ++i) {
      int r = iL[ng * 256 + i];
      float p = pL[ng * 256 + i];
      acc0 += p * xg[(size_t)r * 512 + ltid];
      acc1 += p * xg[(size_t)r * 512 + 256 + ltid];
    }
    acc0 = fmaxf(acc0 + bb, 0.f);
    acc1 = fmaxf(acc1 + bb, 0.f);
    float* hp = ws + WS_H + (size_t)n * 512;
    hp[ltid] = acc0;
    hp[256 + ltid] = acc1;
    red4[ng * 256 + lw * 64 + (ltid & 63)] = acc0 + acc1;
    __syncthreads();
    if (ltid < 64) {
      xm[ng * 64 + ltid] = 0.125f * (red4[ng * 256 + ltid] + red4[ng * 256 + 64 + ltid] +
                                     red4[ng * 256 + 128 + ltid] + red4[ng * 256 + 192 + ltid]);
      float a = p1b[ltid];
      #pragma unroll 4
      for (int kq = 0; kq < 64; ++kq) a += xm[ng * 64 + kq] * sW[kq * 64 + ltid];
      float v = tanhf(a);
      float mx = v;
      #pragma unroll
      for (int m = 32; m; m >>= 1) mx = fmaxf(mx, __shfl_xor(mx, m));
      float e = __expf(v - mx);
      float se = e;
      #pragma unroll
      for (int m = 32; m; m >>= 1) se += __shfl_xor(se, m);
      ws[WS_S1 + (size_t)n * 64 + ltid] = e / se;
    }
    __syncthreads();
  }
}

// ---------------- K3: pool1 with fused AS1+dflat (blks 0..15) + x1 (16..143)
__global__ __launch_bounds__(1024) void k_pool1x1(float* __restrict__ ws) {
  __shared__ float sm[24832];
  int tid = threadIdx.x, blk = blockIdx.x;
  if (blk < 16) {
    int b = blk;
    float* TMPc = sm;            // 16384 (AS1 result, LDS-resident)
    float* dfL  = sm + 16384;    // 256  (dflat, LDS-resident)
    float* scr  = sm + 16640;    // 8192 union: {aL+iLa} then {S1c,prs,...}
    int w = tid >> 6, lane = tid & 63;
    // ---- AS1: each wave computes 16 nodes of Adn@S1 into TMPc
    {
      float* aL = scr;                 // 4096
      int* iLa = (int*)(scr + 4096);   // 4096 ints
      const float* S1g = ws + WS_S1 + ((size_t)b << 8) * 64;
      for (int i = 0; i < 16; ++i) {
        int nl = w * 16 + i;
        int n = (b << 8) + nl;
        float4 av = *(const float4*)(ws + WS_ADN + (size_t)n * 256 + lane * 4);
        float rs = av.x + av.y + av.z + av.w;
        #pragma unroll
        for (int m = 32; m; m >>= 1) rs += __shfl_xor(rs, m);
        if (lane == 0) dfL[nl] = rs;
        float avv[4] = {av.x, av.y, av.z, av.w};
        unsigned long long below = (1ull << lane) - 1ull;
        int base = 0;
        #pragma unroll
        for (int q = 0; q < 4; ++q) {
          bool act = (avv[q] != 0.f);
          unsigned long long mask = __ballot(act);
          if (act) {
            int p = base + (int)__popcll(mask & below);
            iLa[w * 256 + p] = lane * 4 + q;
            aL[w * 256 + p] = avv[q];
          }
          base += (int)__popcll(mask);
        }
        int na = base;
        float acc = 0.f;
        #pragma unroll 4
        for (int i2 = 0; i2 < na; ++i2) {
          int m = iLa[w * 256 + i2];
          float a = aL[w * 256 + i2];
          acc += a * S1g[(size_t)m * 64 + lane];
        }
        TMPc[nl * 64 + lane] = acc;
      }
    }
    __syncthreads();
    // ---- pool1 (T from TMPc, dflat from dfL; S1 staged as before)
    float* S1c = scr;            // 2048
    float* prs = scr + 2048;     // 64*17 = 1088
    float* diagL = scr + 3136;   // 64
    float* dd = scr + 3200;      // 64
    float* red = scr + 3264;     // 16
    const float* Sb = ws + WS_S1 + (size_t)b * 16384;
    int k = tid >> 4, j0 = (tid & 15) * 4;
    float accA[4] = {0, 0, 0, 0}, accS[4] = {0, 0, 0, 0};
    for (int n0 = 0; n0 < 256; n0 += 32) {
      __syncthreads();
      S1c[tid] = Sb[n0 * 64 + tid];
      S1c[tid + 1024] = Sb[n0 * 64 + 1024 + tid];
      __syncthreads();
      for (int i = 0; i < 32; ++i) {
        float sk = S1c[i * 64 + k];
        float4 tv = *(const float4*)(TMPc + (n0 + i) * 64 + j0);
        float4 sv = *(const float4*)(S1c + i * 64 + j0);
        accA[0] += sk * tv.x; accA[1] += sk * tv.y; accA[2] += sk * tv.z; accA[3] += sk * tv.w;
        accS[0] += sk * sv.x; accS[1] += sk * sv.y; accS[2] += sk * sv.z; accS[3] += sk * sv.w;
      }
    }
    float num = 0.f, fro2 = 0.f, rsp = 0.f;
    #pragma unroll
    for (int q = 0; q < 4; ++q) { rsp += accA[q]; fro2 += accS[q] * accS[q]; }
    if (k >= j0 && k < j0 + 4) { num = accA[k - j0]; diagL[k] = accA[k - j0]; }
    prs[k * 17 + (tid & 15)] = rsp;
    __syncthreads();
    if (tid < 64) {
      float rs = 0.f;
      #pragma unroll
      for (int i = 0; i < 16; ++i) rs += prs[tid * 17 + i];
      dd[tid] = sqrtf(fmaxf(rs - diagL[tid], 0.f)) + 1e-15f;
    }
    float denp = 0.f;
    if (tid < 256) {
      const float* s = Sb + tid * 64;
      float qq = 0.f;
      for (int kk = 0; kk < 64; kk += 4) {
        float4 v = *(const float4*)(s + kk);
        qq += v.x * v.x + v.y * v.y + v.z * v.z + v.w * v.w;
      }
      denp = qq * dfL[tid];
    }
    float numT = blockRedSum16(num, red);
    float denT = blockRedSum16(denp, red);
    float froT = sqrtf(blockRedSum16(fro2, red));
    float inv_fro = 1.f / froT;
    float osum = 0.f;
    #pragma unroll
    for (int q = 0; q < 4; ++q) {
      float v = accS[q] * inv_fro - ((j0 + q) == k ? 0.125f : 0.f);
      osum += v * v;
    }
    float orT = blockRedSum16(osum, red);
    float* adj = ws + WS_ADJ1 + (size_t)b * 4096;
    float dk = dd[k];
    #pragma unroll
    for (int q = 0; q < 4; ++q) {
      int j = j0 + q;
      adj[k * 64 + j] = (k == j) ? 0.f : accA[q] / (dk * dd[j]);
    }
    if (tid == 0) {
      ws[WS_SCAL + b] = numT / denT;
      ws[WS_SCAL + 16 + b] = sqrtf(orT);
    }
  } else {
    // x1[b,t,k,h] = sum_n S1[b,n,k] h[b,n,t,h]
    int bt = blk - 16;
    int b = bt >> 3, t = bt & 7;
    int hc = tid & 63, kb = (tid >> 6) * 4;
    float* sS = sm;          // 2048
    float* sX = sm + 2048;   // 2048
    float acc[4] = {0, 0, 0, 0};
    for (int n0 = 0; n0 < 256; n0 += 32) {
      __syncthreads();
      for (int idx = tid; idx < 2048; idx += 1024) {
        int i = idx >> 6, c = idx & 63;
        sS[idx] = ws[WS_S1 + ((size_t)((b << 8) + n0 + i)) * 64 + c];
        sX[idx] = ws[WS_H + ((size_t)((b << 8) + n0 + i)) * 512 + t * 64 + c];
      }
      __syncthreads();
      for (int i = 0; i < 32; ++i) {
        float xv = sX[i * 64 + hc];
        #pragma unroll
        for (int q = 0; q < 4; ++q) acc[q] += sS[i * 64 + kb + q] * xv;
      }
    }
    #pragma unroll
    for (int q = 0; q < 4; ++q)
      ws[WS_X1 + ((size_t)bt * 64 + kb + q) * 64 + hc] = acc[q];
  }
}

// ---------------- K4: conv2 (128 blocks)
__global__ __launch_bounds__(1024) void k_conv2(float* __restrict__ ws,
                                                const float* __restrict__ c2rW,
                                                const float* __restrict__ c2rb,
                                                const float* __restrict__ c2sW) {
  __shared__ float sm[20800];
  int tid = threadIdx.x, blk = blockIdx.x;
  int bt = blk;
  int b = bt >> 3;
  float* sA = sm;
  float* sX = sm + 4160;
  float* sY = sm + 8320;
  float* sWr = sm + 12480;
  float* sWs = sm + 16640;
  for (int idx = tid; idx < 4096; idx += 1024) {
    int r = idx >> 6, c = idx & 63;
    sA[r * 65 + c] = ws[WS_ADJ1 + (size_t)b * 4096 + idx];
    sX[r * 65 + c] = ws[WS_X1 + (size_t)bt * 4096 + idx];
    sWr[r * 65 + c] = c2rW[idx];
    sWs[r * 65 + c] = c2sW[idx];
  }
  __syncthreads();
  int n = tid >> 4, h0 = (tid & 15) * 4;
  float acc[4];
  #pragma unroll
  for (int q = 0; q < 4; ++q) acc[q] = 0.f;
  for (int m = 0; m < 64; ++m) {
    float a = sA[n * 65 + m];
    #pragma unroll
    for (int q = 0; q < 4; ++q) acc[q] += a * sX[m * 65 + h0 + q];
  }
  #pragma unroll
  for (int q = 0; q < 4; ++q) sY[n * 65 + h0 + q] = acc[q];
  __syncthreads();
  #pragma unroll
  for (int q = 0; q < 4; ++q) acc[q] = c2rb[h0 + q];
  for (int m = 0; m < 64; ++m) {
    float y = sY[n * 65 + m], x = sX[n * 65 + m];
    #pragma unroll
    for (int q = 0; q < 4; ++q)
      acc[q] += y * sWr[m * 65 + h0 + q] + x * sWs[m * 65 + h0 + q];
  }
  #pragma unroll
  for (int q = 0; q < 4; ++q)
    ws[WS_X2 + (size_t)bt * 4096 + n * 64 + h0 + q] = fmaxf(acc[q], 0.f);
}

// ---------------- K5: s2 (in LDS) + pool2 fused (16 blocks)
__global__ __launch_bounds__(1024) void k_s2pool2(float* __restrict__ ws,
                                                  const float* __restrict__ p2W,
                                                  const float* __restrict__ p2b) {
  __shared__ float sm[16752];
  int tid = threadIdx.x;
  int b = blockIdx.x;
  float* xmL = sm;            // 4096
  float* sS2 = sm + 4096;     // 64*33 = 2112
  float* sA2 = sm + 6208;     // 64*65 = 4160
  float* sT  = sm + 10368;    // 64*33 = 2112
  float* oaL = sm + 12480;    // 32*33 = 1056
  float* ssL = sm + 13536;    // 32*33 = 1056
  float* sdf = sm + 14592;    // 64
  float* ddL = sm + 14656;    // 32
  float* red = sm + 14688;    // 16
  float* sp2W = sm + 14704;   // 2048
  for (int idx = tid; idx < 4096; idx += 1024)
    sA2[(idx >> 6) * 65 + (idx & 63)] = ws[WS_ADJ1 + (size_t)b * 4096 + idx];
  for (int idx = tid; idx < 2048; idx += 1024) sp2W[idx] = p2W[idx];
  for (int idx = tid; idx < 4096; idx += 1024) {
    int n = idx >> 6, f = idx & 63;
    float s = 0.f;
    #pragma unroll
    for (int t = 0; t < 8; ++t)
      s += ws[WS_X2 + ((size_t)(b * 8 + t) * 64 + n) * 64 + f];
    xmL[idx] = s * 0.125f;
  }
  __syncthreads();
  {
    int n = tid >> 4, j0 = (tid & 15) * 2;
    float a0 = p2b[j0], a1 = p2b[j0 + 1];
    for (int kq = 0; kq < 64; ++kq) {
      float v = xmL[n * 64 + kq];
      a0 += v * sp2W[kq * 32 + j0];
      a1 += v * sp2W[kq * 32 + j0 + 1];
    }
    float v0 = tanhf(a0), v1 = tanhf(a1);
    float mx = fmaxf(v0, v1);
    #pragma unroll
    for (int off = 8; off; off >>= 1) mx = fmaxf(mx, __shfl_xor(mx, off));
    float e0 = __expf(v0 - mx), e1 = __expf(v1 - mx);
    float se = e0 + e1;
    #pragma unroll
    for (int off = 8; off; off >>= 1) se += __shfl_xor(se, off);
    float inv = 1.f / se;
    e0 *= inv; e1 *= inv;
    sS2[n * 33 + j0] = e0;
    sS2[n * 33 + j0 + 1] = e1;
    ws[WS_S2 + (size_t)(b * 64 + n) * 32 + j0] = e0;
    ws[WS_S2 + (size_t)(b * 64 + n) * 32 + j0 + 1] = e1;
  }
  __syncthreads();
  if (tid < 64) {
    float s = 0.f;
    for (int m = 0; m < 64; ++m) s += sA2[tid * 65 + m];
    sdf[tid] = s;
  }
  {
    int n2 = tid >> 4, j0 = (tid & 15) * 2;
    float t0 = 0.f, t1 = 0.f;
    for (int m = 0; m < 64; ++m) {
      float a = sA2[n2 * 65 + m];
      t0 += a * sS2[m * 33 + j0];
      t1 += a * sS2[m * 33 + j0 + 1];
    }
    sT[n2 * 33 + j0] = t0;
    sT[n2 * 33 + j0 + 1] = t1;
  }
  float accD = 0.f;
  if (tid < 64) {
    float t = 0.f;
    for (int q = 0; q < 32; ++q) { float v = sS2[tid * 33 + q]; t += v * v; }
    accD = t * sdf[tid];
  }
  __syncthreads();
  int k5 = tid >> 5, j5 = tid & 31;
  float accA = 0.f, accS = 0.f;
  for (int n3 = 0; n3 < 64; ++n3) {
    float sk = sS2[n3 * 33 + k5];
    accA += sk * sT[n3 * 33 + j5];
    accS += sk * sS2[n3 * 33 + j5];
  }
  oaL[k5 * 33 + j5] = accA;
  ssL[k5 * 33 + j5] = accS;
  float fro2p = accS * accS;
  __syncthreads();
  float num = 0.f, trs = 0.f;
  if (tid < 32) {
    num = oaL[tid * 33 + tid];
    trs = ssL[tid * 33 + tid];
    float rs = 0.f;
    for (int j = 0; j < 32; ++j) rs += oaL[tid * 33 + j];
    ddL[tid] = sqrtf(fmaxf(rs - num, 0.f)) + 1e-15f;
  }
  float numT = blockRedSum16(num, red);
  float denT = blockRedSum16(accD, red);
  float froT = sqrtf(blockRedSum16(fro2p, red));
  float trT = blockRedSum16(trs, red);
  {
    float dk = ddL[k5];
    float* a2 = ws + WS_ADJ2 + (size_t)b * 1024;
    a2[k5 * 32 + j5] = (k5 == j5) ? 0.f : oaL[k5 * 33 + j5] / (dk * ddL[j5]);
  }
  if (tid == 0) {
    ws[WS_SCAL + 32 + b] = numT / denT;
    ws[WS_SCAL + 48 + b] = sqrtf(fmaxf(2.f - 2.f * trT / (5.656854249f * froT), 0.f));
  }
}

// ---------------- K6: x3+conv3 in-LDS (blks 0..127) + agg (128..255) + losses
__global__ __launch_bounds__(1024) void k_final(float* __restrict__ ws,
                                                const float* __restrict__ c3rW,
                                                const float* __restrict__ c3rb,
                                                const float* __restrict__ c3sW,
                                                float* __restrict__ out) {
  __shared__ float sm[19808];
  int tid = threadIdx.x, blk = blockIdx.x;
  if (blk < 128) {
    int bt = blk, b = bt >> 3;
    float* sX  = sm;            // 64*65 = 4160 (X2[bt])
    float* sS  = sm + 4160;     // 64*33 = 2112 (S2[b])
    float* sX3 = sm + 6272;     // 32*65 = 2080
    float* sA  = sm + 8352;     // 32*33 = 1056 (ADJ2[b])
    float* sY  = sm + 9408;     // 32*65 = 2080
    float* sWr = sm + 11488;    // 4160
    float* sWs = sm + 15648;    // 4160 -> 19808
    for (int idx = tid; idx < 4096; idx += 1024)
      sX[(idx >> 6) * 65 + (idx & 63)] = ws[WS_X2 + (size_t)bt * 4096 + idx];
    for (int idx = tid; idx < 2048; idx += 1024)
      sS[(idx >> 5) * 33 + (idx & 31)] = ws[WS_S2 + (size_t)b * 2048 + idx];
    sA[(tid >> 5) * 33 + (tid & 31)] = ws[WS_ADJ2 + (size_t)b * 1024 + tid];
    for (int idx = tid; idx < 4096; idx += 1024) {
      int r = idx >> 6, c = idx & 63;
      sWr[r * 65 + c] = c3rW[idx];
      sWs[r * 65 + c] = c3sW[idx];
    }
    __syncthreads();
    int k = tid >> 5, h0 = (tid & 31) * 2;
    // x3[k][h] = sum_n S2[n][k] * X2[n][h]
    float a0 = 0.f, a1 = 0.f;
    for (int n = 0; n < 64; ++n) {
      float sv = sS[n * 33 + k];
      a0 += sv * sX[n * 65 + h0];
      a1 += sv * sX[n * 65 + h0 + 1];
    }
    sX3[k * 65 + h0] = a0;
    sX3[k * 65 + h0 + 1] = a1;
    __syncthreads();
    // Y[k][h] = sum_m A2[k][m] * X3[m][h]  (m < 32)
    a0 = 0.f; a1 = 0.f;
    for (int m = 0; m < 32; ++m) {
      float a = sA[k * 33 + m];
      a0 += a * sX3[m * 65 + h0];
      a1 += a * sX3[m * 65 + h0 + 1];
    }
    sY[k * 65 + h0] = a0;
    sY[k * 65 + h0 + 1] = a1;
    __syncthreads();
    // out[k][h] = b + sum_m Y[k][m]*Wr[m][h] + X3[k][m]*Ws[m][h]  (m < 64)
    a0 = c3rb[h0]; a1 = c3rb[h0 + 1];
    for (int m = 0; m < 64; ++m) {
      float y = sY[k * 65 + m], x = sX3[k * 65 + m];
      a0 += y * sWr[m * 65 + h0] + x * sWs[m * 65 + h0];
      a1 += y * sWr[m * 65 + h0 + 1] + x * sWs[m * 65 + h0 + 1];
    }
    out[(size_t)bt * 2048 + k * 64 + h0] = a0;
    out[(size_t)bt * 2048 + k * 64 + h0 + 1] = a1;
  } else {
    int rb = blk - 128;
    int b = rb >> 3, sub = rb & 7;
    float* sS = sm;  // 64*33
    for (int idx = tid; idx < 2048; idx += 1024)
      sS[(idx >> 5) * 33 + (idx & 31)] = ws[WS_S2 + (size_t)b * 2048 + idx];
    __syncthreads();
    int n = sub * 32 + (tid >> 5), j = tid & 31;
    const float* s1r = ws + WS_S1 + ((size_t)((b << 8) + n)) * 64;
    float acc = 0.f;
    #pragma unroll 4
    for (int kq = 0; kq < 64; ++kq) acc += s1r[kq] * sS[kq * 33 + j];
    out[262146 + ((size_t)((b << 8) + n)) * 32 + j] = acc;
    if (blk == 255 && tid == 0) {
      float mc = 0.f, o = 0.f;
      #pragma unroll
      for (int b2 = 0; b2 < 16; ++b2) {
        mc += ws[WS_SCAL + b2] + ws[WS_SCAL + 32 + b2];
        o += ws[WS_SCAL + 16 + b2] + ws[WS_SCAL + 48 + b2];
      }
      out[262144] = -mc / 16.0f;
      out[262145] = o / 16.0f;
    }
  }
}

// ================================================================ launch
extern "C" void kernel_launch(void* const* d_in, const int* in_sizes, int n_in,
                              void* d_out, int out_size, void* d_ws, size_t ws_size,
                              hipStream_t stream) {
  (void)in_sizes; (void)n_in; (void)out_size; (void)ws_size;
  const float* pos = (const float*)d_in[0];
  const int* ei = (const int*)d_in[1];
  const float* ea = (const float*)d_in[2];
  const float* W1 = (const float*)d_in[4];
  const float* b1 = (const float*)d_in[5];
  const float* p1W = (const float*)d_in[6];
  const float* p1b = (const float*)d_in[7];
  const float* c2rW = (const float*)d_in[8];
  const float* c2rb = (const float*)d_in[9];
  const float* c2sW = (const float*)d_in[10];
  const float* p2W = (const float*)d_in[11];
  const float* p2b = (const float*)d_in[12];
  const float* c3rW = (const float*)d_in[13];
  const float* c3rb = (const float*)d_in[14];
  const float* c3sW = (const float*)d_in[15];
  float* ws = (float*)d_ws;
  float* out = (float*)d_out;

  // zero WadjT+Adn+wsum (8.4 MB)
  hipMemsetAsync(d_ws, 0, (size_t)2101248 * sizeof(float), stream);
  k_p0<<<dim3(256), dim3(1024), 0, stream>>>(pos, ei, ea, W1, ws);
  k_gcn_s1<<<dim3(256), dim3(1024), 0, stream>>>(ws, b1, p1W, p1b);
  k_pool1x1<<<dim3(144), dim3(1024), 0, stream>>>(ws);
  k_conv2<<<dim3(128), dim3(1024), 0, stream>>>(ws, c2rW, c2rb, c2sW);
  k_s2pool2<<<dim3(16), dim3(1024), 0, stream>>>(ws, p2W, p2b);
  k_final<<<dim3(256), dim3(1024), 0, stream>>>(ws, c3rW, c3rb, c3sW, out);
}